// Round 2
// baseline (799.970 us; speedup 1.0000x reference)
//
#include <hip/hip_runtime.h>

// NoisyLabelLoss: pred (4,12,512,512) f32, cms (4,144,512,512) f32,
// labels (4,512,512) int32. Out: (loss, loss_ce, reg) f32 scalars.
// MIN_TRACE=False -> loss = loss_ce - ALPHA*trace_mean.

constexpr int C  = 12;
constexpr int B  = 4;
constexpr int HW = 512 * 512;
constexpr int IGNORE = 255;
constexpr float EPS = 1e-8f;

__global__ __launch_bounds__(256) void nll_main(
    const float* __restrict__ pred,
    const float* __restrict__ cms,
    const int*   __restrict__ labels,
    double*      __restrict__ acc)   // acc[0]=ce_sum, acc[1]=diag_sum, acc[2]=n_valid
{
    const int gpb = HW / 4;                       // float4 groups per batch image
    const int tid = blockIdx.x * blockDim.x + threadIdx.x;

    float ce = 0.f, dsum = 0.f;
    int   nv = 0;

    if (tid < B * gpb) {
        const int b  = tid / gpb;
        const int p0 = (tid - b * gpb) * 4;

        const float* cb = cms  + (size_t)b * (C * C) * HW + p0;
        const float* pb = pred + (size_t)b * C * HW + p0;
        const int4 lb = *reinterpret_cast<const int4*>(labels + (size_t)b * HW + p0);
        const int l[4] = {lb.x, lb.y, lb.z, lb.w};

        float pn[4] = {0.f, 0.f, 0.f, 0.f};      // pred_noisy at target class

        #pragma unroll
        for (int j = 0; j < C; ++j) {
            float cs[4]  = {0.f, 0.f, 0.f, 0.f}; // colsum over i
            float rl[4]  = {0.f, 0.f, 0.f, 0.f}; // cm[lbl][j]
            float dgv[4] = {0.f, 0.f, 0.f, 0.f}; // cm[j][j]
            #pragma unroll
            for (int i = 0; i < C; ++i) {
                const float4 v4 = *reinterpret_cast<const float4*>(cb + (size_t)(i * C + j) * HW);
                const float v[4] = {v4.x, v4.y, v4.z, v4.w};
                #pragma unroll
                for (int k = 0; k < 4; ++k) {
                    cs[k] += v[k];
                    if (i == j) dgv[k] = v[k];           // compile-time select
                    rl[k] = (l[k] == i) ? v[k] : rl[k];  // row-gather at label
                }
            }
            const float4 p4 = *reinterpret_cast<const float4*>(pb + (size_t)j * HW);
            const float pv[4] = {p4.x, p4.y, p4.z, p4.w};
            #pragma unroll
            for (int k = 0; k < 4; ++k) {
                const float inv = 1.0f / cs[k];          // precise IEEE divide
                pn[k] += rl[k] * inv * pv[k];
                dsum  += dgv[k] * inv;                   // trace term (all pixels)
            }
        }

        #pragma unroll
        for (int k = 0; k < 4; ++k) {
            if (l[k] != IGNORE) {
                ce += logf(pn[k] + EPS);
                nv += 1;
            }
        }
    }

    // wave (64-lane) butterfly reduce
    #pragma unroll
    for (int off = 32; off > 0; off >>= 1) {
        ce   += __shfl_down(ce,   off);
        dsum += __shfl_down(dsum, off);
        nv   += __shfl_down(nv,   off);
    }

    __shared__ float s_ce[4], s_dg[4];
    __shared__ int   s_nv[4];
    const int wave = threadIdx.x >> 6;
    const int lane = threadIdx.x & 63;
    if (lane == 0) { s_ce[wave] = ce; s_dg[wave] = dsum; s_nv[wave] = nv; }
    __syncthreads();
    if (threadIdx.x == 0) {
        float tce = 0.f, tdg = 0.f;
        int   tnv = 0;
        #pragma unroll
        for (int w = 0; w < 4; ++w) { tce += s_ce[w]; tdg += s_dg[w]; tnv += s_nv[w]; }
        atomicAdd(&acc[0], (double)tce);
        atomicAdd(&acc[1], (double)tdg);
        atomicAdd(&acc[2], (double)tnv);
    }
}

__global__ void nll_finalize(const double* __restrict__ acc, float* __restrict__ out)
{
    const double ce = acc[0], dg = acc[1], nv = acc[2];
    const double loss_ce = -ce / (nv > 1.0 ? nv : 1.0);
    const double reg     = 0.1 * dg / (double)((size_t)B * HW);
    out[0] = (float)(loss_ce - reg);   // MIN_TRACE=False
    out[1] = (float)loss_ce;
    out[2] = (float)reg;
}

extern "C" void kernel_launch(void* const* d_in, const int* in_sizes, int n_in,
                              void* d_out, int out_size, void* d_ws, size_t ws_size,
                              hipStream_t stream)
{
    const float* pred   = (const float*)d_in[0];
    const float* cms    = (const float*)d_in[1];
    const int*   labels = (const int*)d_in[2];
    double* acc = (double*)d_ws;
    float*  out = (float*)d_out;

    hipMemsetAsync(acc, 0, 3 * sizeof(double), stream);

    const int total_groups = B * HW / 4;          // 262144 threads
    const int block = 256;
    const int grid  = (total_groups + block - 1) / block;  // 1024 blocks
    nll_main<<<grid, block, 0, stream>>>(pred, cms, labels, acc);
    nll_finalize<<<1, 1, 0, stream>>>(acc, out);
}